// Round 1
// baseline (244.317 us; speedup 1.0000x reference)
//
#include <hip/hip_runtime.h>
#include <hip/hip_fp16.h>

#define BB 16
#define HH 96
#define WW 96
#define CC 128

union U32H2 { unsigned int u; __half2 h; };
__device__ __forceinline__ __half2 u2h2(unsigned int u){ U32H2 t; t.u=u; return t.h; }
__device__ __forceinline__ unsigned int pack2(float x, float y){ U32H2 t; t.h=__floats2half2_rn(x,y); return t.u; }

// -------------------------------------------------------------------------
// Kernel 1: cost volume (81 offsets, mean over 128 ch, leaky relu 0.1)
// -> ws as f16 [B*H*W][96]  (81 real channels + 15 zero pad)
// tile 16x16 px, 128 threads, 2 px per thread (pixel pair along w),
// f16 channel-pair accumulate via v_pk_fma_f16.
// -------------------------------------------------------------------------
__global__ __launch_bounds__(128) void k_cost(const float* __restrict__ prv,
                                              const float* __restrict__ nxt,
                                              __half* __restrict__ cost) {
  const int tw0 = blockIdx.x * 16, th0 = blockIdx.y * 16, b = blockIdx.z;
  const int tid = threadIdx.x;
  const int ty = tid >> 3, txp = tid & 7;       // ty in [0,16), txp in [0,8)

  // layout: [c2 plane][row*24+col] dwords, plane stride 578 (pad vs 576)
  __shared__ unsigned int lds_nxt[8 * 578];
  // prv: [c2 plane][row*16+col] dwords, plane stride 258
  __shared__ unsigned int lds_prv[8 * 258];

  __half2 acc[2][81];
#pragma unroll
  for (int p = 0; p < 2; ++p)
#pragma unroll
    for (int o = 0; o < 81; ++o) acc[p][o] = __float2half2_rn(0.f);

#pragma unroll 1
  for (int cc = 0; cc < 8; ++cc) {              // 8 chunks of 16 channels
    __syncthreads();
    // stage nxt 24x24 region (4-px halo), 16 channels, zero-fill OOB
#pragma unroll 1
    for (int i = tid; i < 24*24*4; i += 128) {
      int c4 = i & 3, pix = i >> 2;
      int row = pix / 24, col = pix - row*24;
      int gr = th0 + row - 4, gc = tw0 + col - 4;
      float4 v = make_float4(0.f,0.f,0.f,0.f);
      if ((unsigned)gr < HH && (unsigned)gc < WW)
        v = *(const float4*)&nxt[(size_t)((b*HH + gr)*WW + gc)*CC + cc*16 + c4*4];
      lds_nxt[(2*c4)*578 + pix]   = pack2(v.x, v.y);
      lds_nxt[(2*c4+1)*578 + pix] = pack2(v.z, v.w);
    }
    // stage prv 16x16 tile
#pragma unroll 1
    for (int i = tid; i < 16*16*4; i += 128) {
      int c4 = i & 3, pix = i >> 2;
      int row = pix >> 4, col = pix & 15;
      const float4 v = *(const float4*)&prv[(size_t)((b*HH + th0+row)*WW + tw0+col)*CC + cc*16 + c4*4];
      lds_prv[(2*c4)*258 + pix]   = pack2(v.x, v.y);
      lds_prv[(2*c4+1)*258 + pix] = pack2(v.z, v.w);
    }
    __syncthreads();
#pragma unroll 1
    for (int c2 = 0; c2 < 8; ++c2) {            // channel pair within chunk
      const uint2 p01 = *(const uint2*)&lds_prv[c2*258 + ty*16 + 2*txp];
      const __half2 p0 = u2h2(p01.x), p1 = u2h2(p01.y);
#pragma unroll
      for (int dy = 0; dy < 9; ++dy) {
        const unsigned int* src = &lds_nxt[c2*578 + (ty+dy)*24 + 2*txp];
        unsigned int v[10];
        *(uint2*)&v[0] = *(const uint2*)&src[0];
        *(uint2*)&v[2] = *(const uint2*)&src[2];
        *(uint2*)&v[4] = *(const uint2*)&src[4];
        *(uint2*)&v[6] = *(const uint2*)&src[6];
        *(uint2*)&v[8] = *(const uint2*)&src[8];
#pragma unroll
        for (int dx = 0; dx < 9; ++dx) {
          acc[0][dy*9+dx] = __hfma2(p0, u2h2(v[dx]),   acc[0][dy*9+dx]);
          acc[1][dy*9+dx] = __hfma2(p1, u2h2(v[dx+1]), acc[1][dy*9+dx]);
        }
      }
    }
  }

  // epilogue: mean (x 1/128), leaky relu, pack to f16, store 96 ch per px
#pragma unroll
  for (int p = 0; p < 2; ++p) {
    unsigned int od[48];
#pragma unroll
    for (int o2 = 0; o2 < 40; ++o2) {
      float a = __low2float(acc[p][2*o2])   + __high2float(acc[p][2*o2]);
      float c = __low2float(acc[p][2*o2+1]) + __high2float(acc[p][2*o2+1]);
      a *= 0.0078125f; a = (a >= 0.f) ? a : 0.1f*a;
      c *= 0.0078125f; c = (c >= 0.f) ? c : 0.1f*c;
      od[o2] = pack2(a, c);
    }
    {
      float a = __low2float(acc[p][80]) + __high2float(acc[p][80]);
      a *= 0.0078125f; a = (a >= 0.f) ? a : 0.1f*a;
      od[40] = pack2(a, 0.f);
    }
#pragma unroll
    for (int o2 = 41; o2 < 48; ++o2) od[o2] = 0u;
    const size_t pix = (size_t)(b*HH + th0+ty)*WW + (tw0 + 2*txp + p);
    uint4* dst = (uint4*)&cost[pix * 96];
#pragma unroll
    for (int q = 0; q < 12; ++q) dst[q] = ((const uint4*)od)[q];
  }
}

// -------------------------------------------------------------------------
// Kernel 2: 3x3 conv over 352 padded channels:
//   ci 0..95  = cost (81 real + 15 zero)
//   ci 96..223  = prv  (conv_w ci 81..208)
//   ci 224..351 = nxt  (conv_w ci 209..336)
// tile 16x16 px, 256 threads, 11 chunks of 32 ch staged as f16 in LDS.
// -------------------------------------------------------------------------
__global__ __launch_bounds__(256) void k_conv(const float* __restrict__ prv,
                                              const float* __restrict__ nxt,
                                              const __half* __restrict__ cost,
                                              const float* __restrict__ cw,
                                              const float* __restrict__ cb,
                                              float* __restrict__ out) {
  const int tw0 = blockIdx.x*16, th0 = blockIdx.y*16, b = blockIdx.z;
  const int tid = threadIdx.x;
  const int ty = tid >> 4, tx = tid & 15;

  __shared__ float w_lds[9*352*2];                 // 25.3 KB, [p][ci][k]
  __shared__ unsigned int lds_feat[18*18*18];      // 23.3 KB: px stride 18 dw (36 f16, padded)

  // stage weights once (zero-extended channel map)
#pragma unroll 1
  for (int i = tid; i < 9*352*2; i += 256) {
    int p = i / 704, r = i - p*704;
    int ci = r >> 1, k = r & 1;
    float v = 0.f;
    if (ci < 81)       v = cw[(p*337 + ci)*2 + k];
    else if (ci >= 96) v = cw[(p*337 + ci - 15)*2 + k];
    w_lds[i] = v;
  }

  float accA0=0.f, accA1=0.f, accB0=0.f, accB1=0.f;
#pragma unroll 1
  for (int chunk = 0; chunk < 11; ++chunk) {
    __syncthreads();
    // stage feat 18x18 halo region, 32 channels of this chunk, as f16
#pragma unroll 1
    for (int i = tid; i < 324*4; i += 256) {
      int j = i & 3, pix = i >> 2;
      int row = pix / 18, col = pix - row*18;
      int gr = th0 + row - 1, gc = tw0 + col - 1;
      uint2 d01 = make_uint2(0u,0u), d23 = make_uint2(0u,0u);
      if ((unsigned)gr < HH && (unsigned)gc < WW) {
        const size_t pixi = (size_t)(b*HH+gr)*WW + gc;
        if (chunk < 3) {
          const uint4 t = *(const uint4*)&cost[pixi*96 + chunk*32 + j*8];
          d01 = make_uint2(t.x, t.y); d23 = make_uint2(t.z, t.w);
        } else {
          const float* src = (chunk < 7) ? prv : nxt;
          const int c0 = ((chunk < 7) ? (chunk-3) : (chunk-7))*32 + j*8;
          const float4 a = *(const float4*)&src[pixi*128 + c0];
          const float4 c = *(const float4*)&src[pixi*128 + c0 + 4];
          d01 = make_uint2(pack2(a.x,a.y), pack2(a.z,a.w));
          d23 = make_uint2(pack2(c.x,c.y), pack2(c.z,c.w));
        }
      }
      *(uint2*)&lds_feat[pix*18 + j*4]     = d01;
      *(uint2*)&lds_feat[pix*18 + j*4 + 2] = d23;
    }
    __syncthreads();
    const int cbase = chunk*32;
#pragma unroll 1
    for (int c4 = 0; c4 < 8; ++c4) {             // 4 channels per step
#pragma unroll
      for (int p = 0; p < 9; ++p) {
        const int ky = p/3, kx = p - ky*3;
        const uint2 f2 = *(const uint2*)&lds_feat[((ty+ky)*18 + (tx+kx))*18 + 2*c4];
        const float2 fa = __half22float2(u2h2(f2.x));
        const float2 fb = __half22float2(u2h2(f2.y));
        const float* wp = &w_lds[p*704 + (cbase + 4*c4)*2];
        const float4 w0 = *(const float4*)wp;
        const float4 w1 = *(const float4*)(wp+4);
        if (p & 1) {
          accB0 += fa.x*w0.x; accB1 += fa.x*w0.y;
          accB0 += fa.y*w0.z; accB1 += fa.y*w0.w;
          accB0 += fb.x*w1.x; accB1 += fb.x*w1.y;
          accB0 += fb.y*w1.z; accB1 += fb.y*w1.w;
        } else {
          accA0 += fa.x*w0.x; accA1 += fa.x*w0.y;
          accA0 += fa.y*w0.z; accA1 += fa.y*w0.w;
          accA0 += fb.x*w1.x; accA1 += fb.x*w1.y;
          accA0 += fb.y*w1.z; accA1 += fb.y*w1.w;
        }
      }
    }
  }
  const float o0 = accA0 + accB0 + cb[0];
  const float o1 = accA1 + accB1 + cb[1];
  float2* dst = (float2*)&out[((size_t)(b*HH + th0+ty)*WW + (tw0+tx))*2];
  *dst = make_float2(o0, o1);
}

extern "C" void kernel_launch(void* const* d_in, const int* in_sizes, int n_in,
                              void* d_out, int out_size, void* d_ws, size_t ws_size,
                              hipStream_t stream) {
  const float* prv = (const float*)d_in[0];
  const float* nxt = (const float*)d_in[1];
  const float* cw  = (const float*)d_in[2];
  const float* cb  = (const float*)d_in[3];
  __half* cost = (__half*)d_ws;   // needs 16*96*96*96*2 = 28,311,552 bytes

  dim3 grid(6, 6, 16);
  k_cost<<<grid, dim3(128), 0, stream>>>(prv, nxt, cost);
  k_conv<<<grid, dim3(256), 0, stream>>>(prv, nxt, cost, cw, cb, (float*)d_out);
}

// Round 2
// 220.924 us; speedup vs baseline: 1.1059x; 1.1059x over previous
//
#include <hip/hip_runtime.h>
#include <hip/hip_fp16.h>

#define BB 16
#define HH 96
#define WW 96
#define CC 128

union U32H2 { unsigned int u; __half2 h; };
__device__ __forceinline__ __half2 u2h2(unsigned int u){ U32H2 t; t.u=u; return t.h; }
__device__ __forceinline__ unsigned int pack2(float x, float y){ U32H2 t; t.h=__floats2half2_rn(x,y); return t.u; }

// -------------------------------------------------------------------------
// Kernel 1: cost volume (81 offsets, mean over 128 ch, leaky relu 0.1)
// -> ws as f16 [B*H*W][96]  (81 real channels + 15 zero pad)
// tile 16x16 px, 256 threads: thread = (px-pair along w, dy-half).
//   h=0: dy 0..4 (45 offsets), h=1: dy 5..8 (36 offsets)
// acc per thread: 2 px * 45 half2 = 90 VGPR -> no spill (was 162 -> spill).
// -------------------------------------------------------------------------
template<int DY0, int NDY>
__device__ __forceinline__ void accum_half(const unsigned int* __restrict__ lds_nxt,
                                           const unsigned int* __restrict__ lds_prv,
                                           int ty, int txp,
                                           __half2 (&a0)[45], __half2 (&a1)[45]) {
#pragma unroll 1
  for (int c2 = 0; c2 < 8; ++c2) {            // channel pair within 16-ch chunk
    const uint2 p01 = *(const uint2*)&lds_prv[c2*258 + ty*16 + 2*txp];
    const __half2 p0 = u2h2(p01.x), p1 = u2h2(p01.y);
#pragma unroll
    for (int dy = 0; dy < NDY; ++dy) {
      const unsigned int* src = &lds_nxt[c2*578 + (ty + DY0 + dy)*24 + 2*txp];
      unsigned int v[10];
      *(uint2*)&v[0] = *(const uint2*)&src[0];
      *(uint2*)&v[2] = *(const uint2*)&src[2];
      *(uint2*)&v[4] = *(const uint2*)&src[4];
      *(uint2*)&v[6] = *(const uint2*)&src[6];
      *(uint2*)&v[8] = *(const uint2*)&src[8];
#pragma unroll
      for (int dx = 0; dx < 9; ++dx) {
        a0[dy*9+dx] = __hfma2(p0, u2h2(v[dx]),   a0[dy*9+dx]);
        a1[dy*9+dx] = __hfma2(p1, u2h2(v[dx+1]), a1[dy*9+dx]);
      }
    }
  }
}

__global__ __launch_bounds__(256) void k_cost(const float* __restrict__ prv,
                                              const float* __restrict__ nxt,
                                              __half* __restrict__ cost) {
  const int tw0 = blockIdx.x * 16, th0 = blockIdx.y * 16, b = blockIdx.z;
  const int tid = threadIdx.x;
  const int pr  = tid & 127, h = tid >> 7;    // pair index, dy-half
  const int ty = pr >> 3, txp = pr & 7;       // ty in [0,16), txp in [0,8)

  // layout: [c2 plane][row*24+col] dwords (1 dword = ch-pair of one px)
  __shared__ unsigned int lds_nxt[8 * 578];
  __shared__ unsigned int lds_prv[8 * 258];

  __half2 a0[45], a1[45];
#pragma unroll
  for (int o = 0; o < 45; ++o) { a0[o] = __float2half2_rn(0.f); a1[o] = __float2half2_rn(0.f); }

#pragma unroll 1
  for (int cc = 0; cc < 8; ++cc) {            // 8 chunks of 16 channels
    __syncthreads();
    // stage nxt 24x24 region (4-px halo): consecutive lanes -> consecutive pix
#pragma unroll 1
    for (int i = tid; i < 24*24*4; i += 256) {
      int c4 = i / 576, pix = i - c4*576;
      int row = pix / 24, col = pix - row*24;
      int gr = th0 + row - 4, gc = tw0 + col - 4;
      float4 v = make_float4(0.f,0.f,0.f,0.f);
      if ((unsigned)gr < HH && (unsigned)gc < WW)
        v = *(const float4*)&nxt[(size_t)((b*HH + gr)*WW + gc)*CC + cc*16 + c4*4];
      lds_nxt[(2*c4)*578 + pix]   = pack2(v.x, v.y);
      lds_nxt[(2*c4+1)*578 + pix] = pack2(v.z, v.w);
    }
    // stage prv 16x16 tile
#pragma unroll 1
    for (int i = tid; i < 16*16*4; i += 256) {
      int c4 = i >> 8, pix = i & 255;
      int row = pix >> 4, col = pix & 15;
      const float4 v = *(const float4*)&prv[(size_t)((b*HH + th0+row)*WW + tw0+col)*CC + cc*16 + c4*4];
      lds_prv[(2*c4)*258 + pix]   = pack2(v.x, v.y);
      lds_prv[(2*c4+1)*258 + pix] = pack2(v.z, v.w);
    }
    __syncthreads();
    if (h == 0) accum_half<0,5>(lds_nxt, lds_prv, ty, txp, a0, a1);
    else        accum_half<5,4>(lds_nxt, lds_prv, ty, txp, a0, a1);
  }

  // epilogue: mean (x 1/128), leaky relu, pack f16, store disjoint ch ranges
  const size_t pix0 = (size_t)(b*HH + th0+ty)*WW + (tw0 + 2*txp);

  if (h == 0) {
    // channels 0..44
    auto wr = [&](const __half2 (&ac)[45], size_t pix) {
      float r[45];
#pragma unroll
      for (int o = 0; o < 45; ++o) {
        float x = __low2float(ac[o]) + __high2float(ac[o]);
        x *= 0.0078125f; r[o] = (x >= 0.f) ? x : 0.1f*x;
      }
      __half* base = &cost[pix * 96];
      unsigned int od[22];
#pragma unroll
      for (int d = 0; d < 22; ++d) od[d] = pack2(r[2*d], r[2*d+1]);
#pragma unroll
      for (int q = 0; q < 5; ++q) ((uint4*)base)[q] = ((const uint4*)od)[q];
      ((uint2*)base)[10] = make_uint2(od[20], od[21]);
      base[44] = __float2half(r[44]);
    };
    wr(a0, pix0); wr(a1, pix0 + 1);
  } else {
    // channels 45..80 (+ zero pad 81..95)
    auto wr = [&](const __half2 (&ac)[45], size_t pix) {
      float r[36];
#pragma unroll
      for (int o = 0; o < 36; ++o) {
        float x = __low2float(ac[o]) + __high2float(ac[o]);
        x *= 0.0078125f; r[o] = (x >= 0.f) ? x : 0.1f*x;
      }
      __half* base = &cost[pix * 96];
      base[45] = __float2half(r[0]);
      ((unsigned int*)base)[23] = pack2(r[1], r[2]);
      unsigned int od[16];
#pragma unroll
      for (int d = 0; d < 16; ++d) od[d] = pack2(r[2*d+3], r[2*d+4]);
#pragma unroll
      for (int q = 0; q < 4; ++q) ((uint4*)base)[6+q] = ((const uint4*)od)[q];
      ((unsigned int*)base)[40] = pack2(r[35], 0.f);
      ((unsigned int*)base)[41] = 0u;
      ((uint2*)base)[21] = make_uint2(0u, 0u);
      ((uint4*)base)[11] = make_uint4(0u,0u,0u,0u);
    };
    wr(a0, pix0); wr(a1, pix0 + 1);
  }
}

// -------------------------------------------------------------------------
// Kernel 2: 3x3 conv over 352 padded channels (unchanged this round):
//   ci 0..95  = cost (81 real + 15 zero)
//   ci 96..223  = prv  (conv_w ci 81..208)
//   ci 224..351 = nxt  (conv_w ci 209..336)
// -------------------------------------------------------------------------
__global__ __launch_bounds__(256) void k_conv(const float* __restrict__ prv,
                                              const float* __restrict__ nxt,
                                              const __half* __restrict__ cost,
                                              const float* __restrict__ cw,
                                              const float* __restrict__ cb,
                                              float* __restrict__ out) {
  const int tw0 = blockIdx.x*16, th0 = blockIdx.y*16, b = blockIdx.z;
  const int tid = threadIdx.x;
  const int ty = tid >> 4, tx = tid & 15;

  __shared__ float w_lds[9*352*2];                 // 25.3 KB, [p][ci][k]
  __shared__ unsigned int lds_feat[18*18*18];      // 23.3 KB: px stride 18 dw

  // stage weights once (zero-extended channel map)
#pragma unroll 1
  for (int i = tid; i < 9*352*2; i += 256) {
    int p = i / 704, r = i - p*704;
    int ci = r >> 1, k = r & 1;
    float v = 0.f;
    if (ci < 81)       v = cw[(p*337 + ci)*2 + k];
    else if (ci >= 96) v = cw[(p*337 + ci - 15)*2 + k];
    w_lds[i] = v;
  }

  float accA0=0.f, accA1=0.f, accB0=0.f, accB1=0.f;
#pragma unroll 1
  for (int chunk = 0; chunk < 11; ++chunk) {
    __syncthreads();
#pragma unroll 1
    for (int i = tid; i < 324*4; i += 256) {
      int j = i & 3, pix = i >> 2;
      int row = pix / 18, col = pix - row*18;
      int gr = th0 + row - 1, gc = tw0 + col - 1;
      uint2 d01 = make_uint2(0u,0u), d23 = make_uint2(0u,0u);
      if ((unsigned)gr < HH && (unsigned)gc < WW) {
        const size_t pixi = (size_t)(b*HH+gr)*WW + gc;
        if (chunk < 3) {
          const uint4 t = *(const uint4*)&cost[pixi*96 + chunk*32 + j*8];
          d01 = make_uint2(t.x, t.y); d23 = make_uint2(t.z, t.w);
        } else {
          const float* src = (chunk < 7) ? prv : nxt;
          const int c0 = ((chunk < 7) ? (chunk-3) : (chunk-7))*32 + j*8;
          const float4 a = *(const float4*)&src[pixi*128 + c0];
          const float4 c = *(const float4*)&src[pixi*128 + c0 + 4];
          d01 = make_uint2(pack2(a.x,a.y), pack2(a.z,a.w));
          d23 = make_uint2(pack2(c.x,c.y), pack2(c.z,c.w));
        }
      }
      *(uint2*)&lds_feat[pix*18 + j*4]     = d01;
      *(uint2*)&lds_feat[pix*18 + j*4 + 2] = d23;
    }
    __syncthreads();
    const int cbase = chunk*32;
#pragma unroll 1
    for (int c4 = 0; c4 < 8; ++c4) {
#pragma unroll
      for (int p = 0; p < 9; ++p) {
        const int ky = p/3, kx = p - ky*3;
        const uint2 f2 = *(const uint2*)&lds_feat[((ty+ky)*18 + (tx+kx))*18 + 2*c4];
        const float2 fa = __half22float2(u2h2(f2.x));
        const float2 fb = __half22float2(u2h2(f2.y));
        const float* wp = &w_lds[p*704 + (cbase + 4*c4)*2];
        const float4 w0 = *(const float4*)wp;
        const float4 w1 = *(const float4*)(wp+4);
        if (p & 1) {
          accB0 += fa.x*w0.x; accB1 += fa.x*w0.y;
          accB0 += fa.y*w0.z; accB1 += fa.y*w0.w;
          accB0 += fb.x*w1.x; accB1 += fb.x*w1.y;
          accB0 += fb.y*w1.z; accB1 += fb.y*w1.w;
        } else {
          accA0 += fa.x*w0.x; accA1 += fa.x*w0.y;
          accA0 += fa.y*w0.z; accA1 += fa.y*w0.w;
          accA0 += fb.x*w1.x; accA1 += fb.x*w1.y;
          accA0 += fb.y*w1.z; accA1 += fb.y*w1.w;
        }
      }
    }
  }
  const float o0 = accA0 + accB0 + cb[0];
  const float o1 = accA1 + accB1 + cb[1];
  float2* dst = (float2*)&out[((size_t)(b*HH + th0+ty)*WW + (tw0+tx))*2];
  *dst = make_float2(o0, o1);
}

extern "C" void kernel_launch(void* const* d_in, const int* in_sizes, int n_in,
                              void* d_out, int out_size, void* d_ws, size_t ws_size,
                              hipStream_t stream) {
  const float* prv = (const float*)d_in[0];
  const float* nxt = (const float*)d_in[1];
  const float* cw  = (const float*)d_in[2];
  const float* cb  = (const float*)d_in[3];
  __half* cost = (__half*)d_ws;   // 16*96*96*96*2 = 28,311,552 bytes

  dim3 grid(6, 6, 16);
  k_cost<<<grid, dim3(256), 0, stream>>>(prv, nxt, cost);
  k_conv<<<grid, dim3(256), 0, stream>>>(prv, nxt, cost, cw, cb, (float*)d_out);
}

// Round 3
// 154.255 us; speedup vs baseline: 1.5839x; 1.4322x over previous
//
#include <hip/hip_runtime.h>
#include <hip/hip_fp16.h>

#define HH 96
#define WW 96
#define CC 128

typedef float f32x4 __attribute__((ext_vector_type(4)));
typedef short short8 __attribute__((ext_vector_type(8)));

union U32H2 { unsigned int u; __half2 h; };
__device__ __forceinline__ __half2 u2h2(unsigned int u){ U32H2 t; t.u=u; return t.h; }
__device__ __forceinline__ unsigned int pack2(float x, float y){ U32H2 t; t.h=__floats2half2_rn(x,y); return t.u; }

// f32 -> bf16 round-to-nearest-even (inputs finite, no NaN handling needed)
__device__ __forceinline__ unsigned short f2bf(float x){
  unsigned int u = __float_as_uint(x);
  return (unsigned short)((u + 0x7FFFu + ((u >> 16) & 1u)) >> 16);
}
__device__ __forceinline__ unsigned int pkbf(float a, float b){
  return (unsigned)f2bf(a) | ((unsigned)f2bf(b) << 16);
}

union U4S8 { uint4 q; short8 s; };

// -------------------------------------------------------------------------
// Kernel 1 (MFMA): cost volume via banded GEMM.
// Per (y, dy): C[16px, 24win] = prv[y,16px,128c] x nxt[y+dy-4, win, 128c]^T
// using mfma_f32_16x16x32_bf16, 2 N-tiles (win padded 24->32), 4 K-steps.
// Block: 512 thr = 8 waves; wave w owns row y0+w. Tile 8y x 16x.
// A-frags: direct from global (f32->bf16 in regs). B: LDS, kq-major layout
//   slot = (r*4+kq)*32 + p  (16B/slot) -> ds_read_b128 conflict-free.
// K double-buffered (2 x 32KB). acc[9dy][2Nt] f32x4 = 72 VGPR, all static.
// Band extract: od = p - m in [0,8]; ch = dy*9+od. ws ch 81..95 unwritten
// (k_conv's weights there are 0; 0xAA f16 poison is finite -> product 0).
// -------------------------------------------------------------------------
__global__ __launch_bounds__(512) void k_cost_mfma(const float* __restrict__ prv,
                                                   const float* __restrict__ nxt,
                                                   __half* __restrict__ cost) {
  const int x0 = blockIdx.x * 16;
  const int y0 = blockIdx.y * 8;
  const int b  = blockIdx.z;
  const int tid = threadIdx.x;
  const int w = tid >> 6, l = tid & 63;
  const int lm = l & 15, lq = l >> 4;
  const int y = y0 + w;

  __shared__ uint4 ntile[2][2048];   // [buf][(r*4+kq)*32 + p], r:16 rows, p:32(24 used)

  f32x4 acc[9][2];
#pragma unroll
  for (int dy = 0; dy < 9; ++dy) {
    acc[dy][0] = (f32x4){0.f,0.f,0.f,0.f};
    acc[dy][1] = (f32x4){0.f,0.f,0.f,0.f};
  }

  // stage 32 channels (kstep ks) of the 16-row x 24-px nxt halo into buf
  auto stage = [&](int ks, int buf){
    const int r = tid >> 5, p = tid & 31;          // r 0..15, p 0..31
    const int gr = y0 - 4 + r, gc = x0 - 4 + p;
    const bool ok = (p < 24) && ((unsigned)gr < HH) && ((unsigned)gc < WW);
    float4 f[8];
#pragma unroll
    for (int j = 0; j < 8; ++j) f[j] = make_float4(0.f,0.f,0.f,0.f);
    if (ok) {
      const float* src = &nxt[((size_t)(b*HH + gr)*WW + gc)*CC + ks*32];
#pragma unroll
      for (int j = 0; j < 8; ++j) f[j] = *(const float4*)(src + j*4);
    }
#pragma unroll
    for (int kq = 0; kq < 4; ++kq) {
      uint4 d;
      d.x = pkbf(f[2*kq].x,   f[2*kq].y);
      d.y = pkbf(f[2*kq].z,   f[2*kq].w);
      d.z = pkbf(f[2*kq+1].x, f[2*kq+1].y);
      d.w = pkbf(f[2*kq+1].z, f[2*kq+1].w);
      ntile[buf][(r*4 + kq)*32 + p] = d;
    }
  };

  stage(0, 0);

#pragma unroll 1
  for (int ks = 0; ks < 4; ++ks) {
    __syncthreads();                    // buf[ks&1] ready; buf[1-(ks&1)] free
    if (ks < 3) stage(ks + 1, (ks + 1) & 1);

    // A-fragment: prv[y, x0+lm, ks*32 + lq*8 .. +7], f32 -> bf16
    const float* ap = &prv[((size_t)(b*HH + y)*WW + x0 + lm)*CC + ks*32 + lq*8];
    const float4 a0 = *(const float4*)ap;
    const float4 a1 = *(const float4*)(ap + 4);
    union { unsigned int u[4]; short8 s; } af;
    af.u[0] = pkbf(a0.x, a0.y); af.u[1] = pkbf(a0.z, a0.w);
    af.u[2] = pkbf(a1.x, a1.y); af.u[3] = pkbf(a1.z, a1.w);

    const int cur = ks & 1;
#pragma unroll
    for (int dy = 0; dy < 9; ++dy) {
      const int sb = ((w + dy)*4 + lq)*32;
      U4S8 b0, b1;
      b0.q = ntile[cur][sb + lm];
      b1.q = ntile[cur][sb + 16 + lm];
      acc[dy][0] = __builtin_amdgcn_mfma_f32_16x16x32_bf16(af.s, b0.s, acc[dy][0], 0, 0, 0);
      acc[dy][1] = __builtin_amdgcn_mfma_f32_16x16x32_bf16(af.s, b1.s, acc[dy][1], 0, 0, 0);
    }
  }

  // band extraction: lane holds C[m = lq*4+reg][p = t*16+lm]; od = p - m
#pragma unroll
  for (int t = 0; t < 2; ++t) {
#pragma unroll
    for (int reg = 0; reg < 4; ++reg) {
      const int m  = lq*4 + reg;
      const int od = t*16 + lm - m;
      if (od >= 0 && od <= 8) {
        __half* bp = &cost[((size_t)(b*HH + y)*WW + x0 + m)*96 + od];
#pragma unroll
        for (int dy = 0; dy < 9; ++dy) {
          float v = acc[dy][t][reg] * 0.0078125f;
          v = (v >= 0.f) ? v : 0.1f * v;
          bp[dy*9] = __float2half(v);
        }
      }
    }
  }
}

// -------------------------------------------------------------------------
// Kernel 2: 3x3 conv over 352 padded channels (unchanged):
//   ci 0..95   = cost (81 real + 15 zero-weight)
//   ci 96..223 = prv  (conv_w ci 81..208)
//   ci 224..351= nxt  (conv_w ci 209..336)
// -------------------------------------------------------------------------
__global__ __launch_bounds__(256) void k_conv(const float* __restrict__ prv,
                                              const float* __restrict__ nxt,
                                              const __half* __restrict__ cost,
                                              const float* __restrict__ cw,
                                              const float* __restrict__ cb,
                                              float* __restrict__ out) {
  const int tw0 = blockIdx.x*16, th0 = blockIdx.y*16, b = blockIdx.z;
  const int tid = threadIdx.x;
  const int ty = tid >> 4, tx = tid & 15;

  __shared__ float w_lds[9*352*2];                 // 25.3 KB, [p][ci][k]
  __shared__ unsigned int lds_feat[18*18*18];      // 23.3 KB: px stride 18 dw

  // stage weights once (zero-extended channel map)
#pragma unroll 1
  for (int i = tid; i < 9*352*2; i += 256) {
    int p = i / 704, r = i - p*704;
    int ci = r >> 1, k = r & 1;
    float v = 0.f;
    if (ci < 81)       v = cw[(p*337 + ci)*2 + k];
    else if (ci >= 96) v = cw[(p*337 + ci - 15)*2 + k];
    w_lds[i] = v;
  }

  float accA0=0.f, accA1=0.f, accB0=0.f, accB1=0.f;
#pragma unroll 1
  for (int chunk = 0; chunk < 11; ++chunk) {
    __syncthreads();
#pragma unroll 1
    for (int i = tid; i < 324*4; i += 256) {
      int j = i & 3, pix = i >> 2;
      int row = pix / 18, col = pix - row*18;
      int gr = th0 + row - 1, gc = tw0 + col - 1;
      uint2 d01 = make_uint2(0u,0u), d23 = make_uint2(0u,0u);
      if ((unsigned)gr < HH && (unsigned)gc < WW) {
        const size_t pixi = (size_t)(b*HH+gr)*WW + gc;
        if (chunk < 3) {
          const uint4 t = *(const uint4*)&cost[pixi*96 + chunk*32 + j*8];
          d01 = make_uint2(t.x, t.y); d23 = make_uint2(t.z, t.w);
        } else {
          const float* src = (chunk < 7) ? prv : nxt;
          const int c0 = ((chunk < 7) ? (chunk-3) : (chunk-7))*32 + j*8;
          const float4 a = *(const float4*)&src[pixi*128 + c0];
          const float4 c = *(const float4*)&src[pixi*128 + c0 + 4];
          d01 = make_uint2(pack2(a.x,a.y), pack2(a.z,a.w));
          d23 = make_uint2(pack2(c.x,c.y), pack2(c.z,c.w));
        }
      }
      *(uint2*)&lds_feat[pix*18 + j*4]     = d01;
      *(uint2*)&lds_feat[pix*18 + j*4 + 2] = d23;
    }
    __syncthreads();
    const int cbase = chunk*32;
#pragma unroll 1
    for (int c4 = 0; c4 < 8; ++c4) {
#pragma unroll
      for (int p = 0; p < 9; ++p) {
        const int ky = p/3, kx = p - ky*3;
        const uint2 f2 = *(const uint2*)&lds_feat[((ty+ky)*18 + (tx+kx))*18 + 2*c4];
        const float2 fa = __half22float2(u2h2(f2.x));
        const float2 fb = __half22float2(u2h2(f2.y));
        const float* wp = &w_lds[p*704 + (cbase + 4*c4)*2];
        const float4 w0 = *(const float4*)wp;
        const float4 w1 = *(const float4*)(wp+4);
        if (p & 1) {
          accB0 += fa.x*w0.x; accB1 += fa.x*w0.y;
          accB0 += fa.y*w0.z; accB1 += fa.y*w0.w;
          accB0 += fb.x*w1.x; accB1 += fb.x*w1.y;
          accB0 += fb.y*w1.z; accB1 += fb.y*w1.w;
        } else {
          accA0 += fa.x*w0.x; accA1 += fa.x*w0.y;
          accA0 += fa.y*w0.z; accA1 += fa.y*w0.w;
          accA0 += fb.x*w1.x; accA1 += fb.x*w1.y;
          accA0 += fb.y*w1.z; accA1 += fb.y*w1.w;
        }
      }
    }
  }
  const float o0 = accA0 + accB0 + cb[0];
  const float o1 = accA1 + accB1 + cb[1];
  float2* dst = (float2*)&out[((size_t)(b*HH + th0+ty)*WW + (tw0+tx))*2];
  *dst = make_float2(o0, o1);
}

extern "C" void kernel_launch(void* const* d_in, const int* in_sizes, int n_in,
                              void* d_out, int out_size, void* d_ws, size_t ws_size,
                              hipStream_t stream) {
  const float* prv = (const float*)d_in[0];
  const float* nxt = (const float*)d_in[1];
  const float* cw  = (const float*)d_in[2];
  const float* cb  = (const float*)d_in[3];
  __half* cost = (__half*)d_ws;   // 16*96*96*96*2 = 28,311,552 bytes

  k_cost_mfma<<<dim3(6, 12, 16), dim3(512), 0, stream>>>(prv, nxt, cost);
  k_conv<<<dim3(6, 6, 16), dim3(256), 0, stream>>>(prv, nxt, cost, cw, cb, (float*)d_out);
}

// Round 4
// 104.688 us; speedup vs baseline: 2.3338x; 1.4735x over previous
//
#include <hip/hip_runtime.h>
#include <hip/hip_fp16.h>

#define HH 96
#define WW 96
#define CC 128

typedef float f32x4 __attribute__((ext_vector_type(4)));
typedef short short8 __attribute__((ext_vector_type(8)));
typedef _Float16 f16x8 __attribute__((ext_vector_type(8)));

union U32H2 { unsigned int u; __half2 h; };
__device__ __forceinline__ unsigned int pack2(float x, float y){ U32H2 t; t.h=__floats2half2_rn(x,y); return t.u; }

// f32 -> bf16 round-to-nearest-even
__device__ __forceinline__ unsigned short f2bf(float x){
  unsigned int u = __float_as_uint(x);
  return (unsigned short)((u + 0x7FFFu + ((u >> 16) & 1u)) >> 16);
}
__device__ __forceinline__ unsigned int pkbf(float a, float b){
  return (unsigned)f2bf(a) | ((unsigned)f2bf(b) << 16);
}

union U4S8 { uint4 q; short8 s; };
union U4H8 { uint4 q; f16x8 h; };

// -------------------------------------------------------------------------
// Kernel 1 (MFMA): cost volume via banded GEMM.  (unchanged from round 3)
// -------------------------------------------------------------------------
__global__ __launch_bounds__(512) void k_cost_mfma(const float* __restrict__ prv,
                                                   const float* __restrict__ nxt,
                                                   __half* __restrict__ cost) {
  const int x0 = blockIdx.x * 16;
  const int y0 = blockIdx.y * 8;
  const int b  = blockIdx.z;
  const int tid = threadIdx.x;
  const int w = tid >> 6, l = tid & 63;
  const int lm = l & 15, lq = l >> 4;
  const int y = y0 + w;

  __shared__ uint4 ntile[2][2048];

  f32x4 acc[9][2];
#pragma unroll
  for (int dy = 0; dy < 9; ++dy) {
    acc[dy][0] = (f32x4){0.f,0.f,0.f,0.f};
    acc[dy][1] = (f32x4){0.f,0.f,0.f,0.f};
  }

  auto stage = [&](int ks, int buf){
    const int r = tid >> 5, p = tid & 31;
    const int gr = y0 - 4 + r, gc = x0 - 4 + p;
    const bool ok = (p < 24) && ((unsigned)gr < HH) && ((unsigned)gc < WW);
    float4 f[8];
#pragma unroll
    for (int j = 0; j < 8; ++j) f[j] = make_float4(0.f,0.f,0.f,0.f);
    if (ok) {
      const float* src = &nxt[((size_t)(b*HH + gr)*WW + gc)*CC + ks*32];
#pragma unroll
      for (int j = 0; j < 8; ++j) f[j] = *(const float4*)(src + j*4);
    }
#pragma unroll
    for (int kq = 0; kq < 4; ++kq) {
      uint4 d;
      d.x = pkbf(f[2*kq].x,   f[2*kq].y);
      d.y = pkbf(f[2*kq].z,   f[2*kq].w);
      d.z = pkbf(f[2*kq+1].x, f[2*kq+1].y);
      d.w = pkbf(f[2*kq+1].z, f[2*kq+1].w);
      ntile[buf][(r*4 + kq)*32 + p] = d;
    }
  };

  stage(0, 0);

#pragma unroll 1
  for (int ks = 0; ks < 4; ++ks) {
    __syncthreads();
    if (ks < 3) stage(ks + 1, (ks + 1) & 1);

    const float* ap = &prv[((size_t)(b*HH + y)*WW + x0 + lm)*CC + ks*32 + lq*8];
    const float4 a0 = *(const float4*)ap;
    const float4 a1 = *(const float4*)(ap + 4);
    union { unsigned int u[4]; short8 s; } af;
    af.u[0] = pkbf(a0.x, a0.y); af.u[1] = pkbf(a0.z, a0.w);
    af.u[2] = pkbf(a1.x, a1.y); af.u[3] = pkbf(a1.z, a1.w);

    const int cur = ks & 1;
#pragma unroll
    for (int dy = 0; dy < 9; ++dy) {
      const int sb = ((w + dy)*4 + lq)*32;
      U4S8 b0, b1;
      b0.q = ntile[cur][sb + lm];
      b1.q = ntile[cur][sb + 16 + lm];
      acc[dy][0] = __builtin_amdgcn_mfma_f32_16x16x32_bf16(af.s, b0.s, acc[dy][0], 0, 0, 0);
      acc[dy][1] = __builtin_amdgcn_mfma_f32_16x16x32_bf16(af.s, b1.s, acc[dy][1], 0, 0, 0);
    }
  }

#pragma unroll
  for (int t = 0; t < 2; ++t) {
#pragma unroll
    for (int reg = 0; reg < 4; ++reg) {
      const int m  = lq*4 + reg;
      const int od = t*16 + lm - m;
      if (od >= 0 && od <= 8) {
        __half* bp = &cost[((size_t)(b*HH + y)*WW + x0 + m)*96 + od];
#pragma unroll
        for (int dy = 0; dy < 9; ++dy) {
          float v = acc[dy][t][reg] * 0.0078125f;
          v = (v >= 0.f) ? v : 0.1f * v;
          bp[dy*9] = __float2half(v);
        }
      }
    }
  }
}

// -------------------------------------------------------------------------
// Kernel 2 (MFMA): conv as GEMM + gather.
// G[px, j=tap*2+n] = sum_k feat[px,k] * W[tap,k,n]   (M=324 halo px, K=352, N=18->32)
// out[y,x,n] = cb[n] + sum_tap G[y+dy-1, x+dx-1, tap*2+n]
// feat channels: 0..95 cost(f16 ws, 81 real), 96..223 prv, 224..351 nxt.
// Block: 512 thr = 8 waves, 16x16 out tile, 18x18 halo (21 M-frags).
// LDS: feat chunk [336 px][40 half] (stride 40 -> aligned b128, bank-spread);
//      B2 [11 kc][4 lq][32 j] uint4 (k-major, conflict-free);
//      G [324][20] f32 aliases feat buffer after K-loop.  Total 48.25 KB.
// -------------------------------------------------------------------------
__global__ __launch_bounds__(512) void k_conv_gemm(const float* __restrict__ prv,
                                                   const float* __restrict__ nxt,
                                                   const __half* __restrict__ cost,
                                                   const float* __restrict__ cw,
                                                   const float* __restrict__ cb,
                                                   float* __restrict__ out) {
  const int tw0 = blockIdx.x*16, th0 = blockIdx.y*16, b = blockIdx.z;
  const int tid = threadIdx.x;
  const int w = tid >> 6, l = tid & 63;
  const int lm = l & 15, lq = l >> 4;

  __shared__ __align__(16) char smem[49408];
  __half*       featH  = (__half*)smem;              // [336][40] halves (26880 B)
  uint4*        feat16 = (uint4*)smem;               // idx = 5*px + (16B unit)
  float*        Gf     = (float*)smem;               // [324][20] f32 (aliased)
  float2*       Gf2    = (float2*)smem;
  uint4*        B2     = (uint4*)(smem + 26880);     // [(kc*4+lq)*32 + j] (22528 B)
  __half*       B2h    = (__half*)(smem + 26880);

  // one-time: zero B2, zero feat pad rows (px 324..335)
#pragma unroll 1
  for (int i = tid; i < 5632; i += 512) ((unsigned int*)B2)[i] = 0u;
#pragma unroll 1
  for (int i = tid; i < 240; i += 512) ((unsigned int*)smem)[6480 + i] = 0u;
  // fill weights: entry (ci, j): tap=j>>1, n=j&1
#pragma unroll 1
  for (int i = tid; i < 352*18; i += 512) {
    const int ci = i / 18, j = i - 18*ci;
    if (ci >= 81 && ci < 96) continue;
    const int wci = (ci < 81) ? ci : ci - 15;
    const int tap = j >> 1, n = j & 1;
    const float v = cw[(tap*337 + wci)*2 + n];
    const int kk = ci & 31;
    B2h[((((ci >> 5)*4 + (kk >> 3))*32) + j)*8 + (kk & 7)] = __float2half(v);
  }

  f32x4 acc[3][2];
#pragma unroll
  for (int i = 0; i < 3; ++i) { acc[i][0] = (f32x4){0,0,0,0}; acc[i][1] = (f32x4){0,0,0,0}; }

#pragma unroll 1
  for (int kc = 0; kc < 11; ++kc) {
    __syncthreads();          // previous readers of featH done (covers B2 fill at kc=0)
    // stage feat chunk kc: 324 halo px x 32 ch -> f16
#pragma unroll 1
    for (int i = tid; i < 648; i += 512) {
      const int px = i >> 1, half = i & 1;
      const int hr = px / 18, hc = px - 18*hr;
      const int gr = th0 - 1 + hr, gc = tw0 - 1 + hc;
      uint4 d0 = make_uint4(0,0,0,0), d1 = make_uint4(0,0,0,0);
      if ((unsigned)gr < HH && (unsigned)gc < WW) {
        const size_t pixi = (size_t)(b*HH + gr)*WW + gc;
        if (kc < 3) {
          const uint4* cs = (const uint4*)&cost[pixi*96 + kc*32 + half*16];
          d0 = cs[0]; d1 = cs[1];
        } else {
          const float* src = (kc < 7) ? prv : nxt;
          const int c0 = ((kc < 7) ? (kc-3) : (kc-7))*32 + half*16;
          const float4 f0 = *(const float4*)&src[pixi*128 + c0];
          const float4 f1 = *(const float4*)&src[pixi*128 + c0 + 4];
          const float4 f2 = *(const float4*)&src[pixi*128 + c0 + 8];
          const float4 f3 = *(const float4*)&src[pixi*128 + c0 + 12];
          d0 = make_uint4(pack2(f0.x,f0.y), pack2(f0.z,f0.w), pack2(f1.x,f1.y), pack2(f1.z,f1.w));
          d1 = make_uint4(pack2(f2.x,f2.y), pack2(f2.z,f2.w), pack2(f3.x,f3.y), pack2(f3.z,f3.w));
        }
      }
      feat16[5*px + 2*half]     = d0;
      feat16[5*px + 2*half + 1] = d1;
    }
    __syncthreads();

    // B-frags for this kc (shared across M-frags)
    U4H8 bf0, bf1;
    bf0.q = B2[(kc*4 + lq)*32 + lm];
    bf1.q = B2[(kc*4 + lq)*32 + 16 + lm];
#pragma unroll
    for (int i = 0; i < 3; ++i) {
      const int mf = w + 8*i;
      if (mf < 21) {
        U4H8 af;
        af.q = feat16[5*(16*mf + lm) + lq];
        acc[i][0] = __builtin_amdgcn_mfma_f32_16x16x32_f16(af.h, bf0.h, acc[i][0], 0, 0, 0);
        acc[i][1] = __builtin_amdgcn_mfma_f32_16x16x32_f16(af.h, bf1.h, acc[i][1], 0, 0, 0);
      }
    }
  }
  __syncthreads();            // all MFMA A-reads done before aliasing featH with G

  // write G: lane holds C[m=lq*4+r][j=nf*16+lm] for frag mf
#pragma unroll
  for (int i = 0; i < 3; ++i) {
    const int mf = w + 8*i;
    if (mf >= 21) continue;
#pragma unroll
    for (int r = 0; r < 4; ++r) {
      const int px = 16*mf + lq*4 + r;
      if (px < 324) {
        Gf[px*20 + lm] = acc[i][0][r];            // j = lm (0..15)
        if (lm < 2) Gf[px*20 + 16 + lm] = acc[i][1][r];  // j = 16,17
      }
    }
  }
  __syncthreads();

  // gather: thread -> (out px, n);  out = cb[n] + sum_tap G[hp][2*tap+n]
  if (tid < 512) {
    const int px = tid >> 1, n = tid & 1;
    const int ty = px >> 4, tx = px & 15;
    float s = cb[n];
#pragma unroll
    for (int p = 0; p < 9; ++p) {
      const int dy = p / 3, dx = p - 3*dy;
      const int hp = (ty + dy)*18 + (tx + dx);
      const float2 g = Gf2[hp*10 + p];
      s += n ? g.y : g.x;
    }
    out[((size_t)(b*HH + th0 + ty)*WW + (tw0 + tx))*2 + n] = s;
  }
}

extern "C" void kernel_launch(void* const* d_in, const int* in_sizes, int n_in,
                              void* d_out, int out_size, void* d_ws, size_t ws_size,
                              hipStream_t stream) {
  const float* prv = (const float*)d_in[0];
  const float* nxt = (const float*)d_in[1];
  const float* cw  = (const float*)d_in[2];
  const float* cb  = (const float*)d_in[3];
  __half* cost = (__half*)d_ws;   // 16*96*96*96*2 = 28,311,552 bytes

  k_cost_mfma<<<dim3(6, 12, 16), dim3(512), 0, stream>>>(prv, nxt, cost);
  k_conv_gemm<<<dim3(6, 6, 16), dim3(512), 0, stream>>>(prv, nxt, cost, cw, cb, (float*)d_out);
}